// Round 4
// baseline (116.120 us; speedup 1.0000x reference)
//
#include <hip/hip_runtime.h>
#include <cstdint>

#define EPS_IOU 1e-6f
#define PPT 4              // pred rows per thread

// Prep: per-gt area (+eps); also zero the output scalar.
__global__ __launch_bounds__(256) void k_prep(
    const float4* __restrict__ gt, float* __restrict__ gae, int M,
    float* __restrict__ out)
{
    int j = blockIdx.x * 256 + threadIdx.x;
    if (j < M) {
        float4 g = gt[j];
        gae[j] = (g.z - g.x) * (g.w - g.y) + EPS_IOU;
    }
    if (blockIdx.x == 0 && threadIdx.x == 0) out[0] = 0.0f;
}

// 4 pred rows per thread (strided 256 within the block's 1024-row span),
// gt chunk per blockIdx.y. j is wave-uniform -> gt box + area arrive via
// scalar loads, each amortized over 4*64 pairs.
// Test: iou >= 0.5  <=>  2*inter >= union+eps  <=>  3*inter >= a1+ga+eps.
__global__ __launch_bounds__(256) void k_pairwise(
    const float4* __restrict__ pred, const float4* __restrict__ gt,
    const float* __restrict__ gae, uint8_t* __restrict__ flags,
    int N, int M, int Mc)
{
    int base = blockIdx.x * (256 * PPT) + threadIdx.x;
    float4 b[PPT]; float a1[PPT];
    #pragma unroll
    for (int k = 0; k < PPT; ++k) {
        int i = base + k * 256;
        int ii = i < N ? i : N - 1;        // clamp read; store is guarded
        b[k] = pred[ii];
        a1[k] = (b[k].z - b[k].x) * (b[k].w - b[k].y);
    }

    int j0 = blockIdx.y * Mc;
    int j1 = j0 + Mc; if (j1 > M) j1 = M;

    bool found[PPT] = {false, false, false, false};
    #pragma unroll 4
    for (int j = j0; j < j1; ++j) {
        float4 g  = gt[j];                 // uniform -> s_load_dwordx4
        float ga  = gae[j];                // uniform -> s_load_dword
        #pragma unroll
        for (int k = 0; k < PPT; ++k) {
            float rhs = a1[k] + ga;
            float dx  = fmaxf(fminf(b[k].z, g.z) - fmaxf(b[k].x, g.x), 0.0f);
            float dy  = fmaxf(fminf(b[k].w, g.w) - fmaxf(b[k].y, g.y), 0.0f);
            found[k] |= (fmaf(dx * dy, 3.0f, -rhs) >= 0.0f);
        }
    }
    #pragma unroll
    for (int k = 0; k < PPT; ++k) {
        int i = base + k * 256;
        if (i < N) flags[blockIdx.y * N + i] = found[k] ? (uint8_t)1 : (uint8_t)0;
    }
}

// OR the chunk flags (runtime count), BCE term per row, reduce, atomicAdd.
__global__ __launch_bounds__(256) void k_loss(
    const float* __restrict__ scores, const uint8_t* __restrict__ flags,
    float* __restrict__ out, int N, int chunks)
{
    float acc = 0.0f;
    for (int i = blockIdx.x * 256 + threadIdx.x; i < N; i += gridDim.x * 256) {
        int f = 0;
        for (int c = 0; c < chunks; ++c) f |= flags[c * N + i];
        float p  = scores[i];
        float lp = fmaxf(logf(p),    -100.0f);
        float l1 = fmaxf(log1pf(-p), -100.0f);
        acc += f ? lp : l1;
    }
    for (int o = 32; o > 0; o >>= 1) acc += __shfl_down(acc, o, 64);
    __shared__ float sm[4];
    int lane = threadIdx.x & 63, w = threadIdx.x >> 6;
    if (lane == 0) sm[w] = acc;
    __syncthreads();
    if (threadIdx.x == 0) {
        float s = sm[0] + sm[1] + sm[2] + sm[3];
        atomicAdd(out, -s / (float)N);
    }
}

extern "C" void kernel_launch(void* const* d_in, const int* in_sizes, int n_in,
                              void* d_out, int out_size, void* d_ws, size_t ws_size,
                              hipStream_t stream) {
    const float*  scores = (const float*)d_in[0];
    const float4* pred   = (const float4*)d_in[1];
    const float4* gt     = (const float4*)d_in[2];
    float* out = (float*)d_out;

    int N = in_sizes[0];          // 20000 pred rows
    int M = in_sizes[2] / 4;      // 4000 gt boxes

    float*   gae   = (float*)d_ws;                 // 16 KB
    uint8_t* flags = (uint8_t*)d_ws + 16384;

    // Runtime chunk count, capped by available workspace.
    int chunks = 80;
    size_t avail = ws_size > 16384 ? ws_size - 16384 : 0;
    long maxc = (long)(avail / (size_t)N);
    if (maxc < 1) maxc = 1;
    if (chunks > maxc) chunks = (int)maxc;
    int Mc = (M + chunks - 1) / chunks;

    k_prep<<<dim3((M + 255) / 256), dim3(256), 0, stream>>>(gt, gae, M, out);

    int bx = (N + 256 * PPT - 1) / (256 * PPT);    // 20 for N=20000
    dim3 g1(bx, chunks);
    k_pairwise<<<g1, dim3(256), 0, stream>>>(pred, gt, gae, flags, N, M, Mc);

    k_loss<<<dim3(80), dim3(256), 0, stream>>>(scores, flags, out, N, chunks);
}

// Round 5
// 111.145 us; speedup vs baseline: 1.0448x; 1.0448x over previous
//
#include <hip/hip_runtime.h>
#include <cstdint>

#define EPS_IOU 1e-6f
#define NB 64              // x1 bins for counting sort
#define XMAX 901.0f
#define CCH 32             // window chunks (grid.y), power of 2
#define LOG2_CCH 5

// Single-block prep: counting-sort gt and pred by x1, precompute areas,
// zero flags and the output scalar.
__global__ __launch_bounds__(1024) void k_prep(
    const float4* __restrict__ pred, const float4* __restrict__ gt,
    int N, int M,
    float4* __restrict__ sgt, float* __restrict__ sga,
    float4* __restrict__ spred, float* __restrict__ spa, int* __restrict__ sidx,
    unsigned* __restrict__ flags, unsigned* __restrict__ bin_start,
    float* __restrict__ out)
{
    __shared__ unsigned hist[NB], cur[NB];
    const float scale = (float)NB / XMAX;
    int tid = threadIdx.x;

    // ---- gt: histogram ----
    if (tid < NB) hist[tid] = 0;
    __syncthreads();
    for (int j = tid; j < M; j += 1024) {
        int b = (int)(gt[j].x * scale); b = b < 0 ? 0 : (b > NB - 1 ? NB - 1 : b);
        atomicAdd(&hist[b], 1u);
    }
    __syncthreads();
    if (tid == 0) {
        unsigned run = 0;
        for (int b = 0; b < NB; ++b) { unsigned h = hist[b]; cur[b] = run; bin_start[b] = run; run += h; }
        bin_start[NB] = run;
        out[0] = 0.0f;
    }
    __syncthreads();
    // ---- gt: scatter (order within bin irrelevant) ----
    for (int j = tid; j < M; j += 1024) {
        float4 g = gt[j];
        int b = (int)(g.x * scale); b = b < 0 ? 0 : (b > NB - 1 ? NB - 1 : b);
        unsigned pos = atomicAdd(&cur[b], 1u);
        sgt[pos] = g;
        sga[pos] = (g.z - g.x) * (g.w - g.y) + EPS_IOU;   // ga + eps
    }
    __syncthreads();

    // ---- pred: histogram ----
    if (tid < NB) hist[tid] = 0;
    __syncthreads();
    for (int i = tid; i < N; i += 1024) {
        int b = (int)(pred[i].x * scale); b = b < 0 ? 0 : (b > NB - 1 ? NB - 1 : b);
        atomicAdd(&hist[b], 1u);
    }
    __syncthreads();
    if (tid == 0) {
        unsigned run = 0;
        for (int b = 0; b < NB; ++b) { unsigned h = hist[b]; cur[b] = run; run += h; }
    }
    __syncthreads();
    // ---- pred: scatter ----
    for (int i = tid; i < N; i += 1024) {
        float4 p = pred[i];
        int b = (int)(p.x * scale); b = b < 0 ? 0 : (b > NB - 1 ? NB - 1 : b);
        unsigned pos = atomicAdd(&cur[b], 1u);
        spred[pos] = p;
        spa[pos] = (p.z - p.x) * (p.w - p.y);
        sidx[pos] = (int)i;
    }
    // ---- zero flags ----
    for (int i = tid; i < N; i += 1024) flags[i] = 0u;
}

// 2 sorted pred ranks per thread; wave computes a shared x-window over its
// 512-rank span, scans only gt whose x1 falls in the window (wave-uniform j
// -> scalar loads). grid.y slices the window for parallelism.
// hit test: iou >= 0.5  <=>  3*inter >= a1+ga+eps  <=>  fma(inter,3,-a1) >= ga'
__global__ __launch_bounds__(256) void k_pair(
    const float4* __restrict__ spred, const float* __restrict__ spa,
    const float4* __restrict__ sgt, const float* __restrict__ sga,
    const unsigned* __restrict__ bin_start, unsigned* __restrict__ flags,
    int N)
{
    const float scale = (float)NB / XMAX;
    int tid = threadIdx.x;
    int r0 = blockIdx.x * 512 + tid;
    int r1 = r0 + 256;
    int rr0 = r0 < N ? r0 : N - 1;
    int rr1 = r1 < N ? r1 : N - 1;
    float4 b0 = spred[rr0], b1 = spred[rr1];
    float a0 = spa[rr0], a1 = spa[rr1];

    // conservative window: gt overlaps only if gx1 in [bx1-101, bx2] (+1px slack)
    float lo = fminf(b0.x, b1.x) - 102.0f;
    float hi = fmaxf(b0.z, b1.z) + 1.0f;
    #pragma unroll
    for (int m = 32; m >= 1; m >>= 1) {
        lo = fminf(lo, __shfl_xor(lo, m, 64));
        hi = fmaxf(hi, __shfl_xor(hi, m, 64));
    }
    int ilo = (int)(lo * scale); ilo = ilo < 0 ? 0 : (ilo > NB - 1 ? NB - 1 : ilo);
    int ihi = (int)(hi * scale); ihi = ihi < 0 ? 0 : (ihi > NB - 1 ? NB - 1 : ihi);
    ilo = __builtin_amdgcn_readfirstlane(ilo);
    ihi = __builtin_amdgcn_readfirstlane(ihi);
    int js0 = (int)bin_start[ilo];
    int je0 = (int)bin_start[ihi + 1];
    int len = je0 - js0;
    int c = (int)blockIdx.y;
    int js = js0 + ((len * c) >> LOG2_CCH);
    int je = js0 + ((len * (c + 1)) >> LOG2_CCH);

    bool f0 = false, f1 = false;
    #pragma unroll 4
    for (int j = js; j < je; ++j) {
        float4 g = sgt[j];                 // uniform -> s_load_dwordx4
        float ga = sga[j];                 // uniform -> s_load_dword
        {
            float dx = fmaxf(fminf(b0.z, g.z) - fmaxf(b0.x, g.x), 0.0f);
            float dy = fmaxf(fminf(b0.w, g.w) - fmaxf(b0.y, g.y), 0.0f);
            f0 |= (fmaf(dx * dy, 3.0f, -a0) >= ga);
        }
        {
            float dx = fmaxf(fminf(b1.z, g.z) - fmaxf(b1.x, g.x), 0.0f);
            float dy = fmaxf(fminf(b1.w, g.w) - fmaxf(b1.y, g.y), 0.0f);
            f1 |= (fmaf(dx * dy, 3.0f, -a1) >= ga);
        }
    }
    if (f0 && r0 < N) atomicOr(&flags[r0], 1u);
    if (f1 && r1 < N) atomicOr(&flags[r1], 1u);
}

// Per-rank BCE with score gathered via sidx; mean is order-independent.
__global__ __launch_bounds__(256) void k_loss(
    const float* __restrict__ scores, const unsigned* __restrict__ flags,
    const int* __restrict__ sidx, float* __restrict__ out, int N)
{
    float acc = 0.0f;
    for (int r = blockIdx.x * 256 + threadIdx.x; r < N; r += gridDim.x * 256) {
        float p = scores[sidx[r]];
        float lp = fmaxf(logf(p),    -100.0f);
        float l1 = fmaxf(log1pf(-p), -100.0f);
        acc += flags[r] ? lp : l1;
    }
    for (int o = 32; o > 0; o >>= 1) acc += __shfl_down(acc, o, 64);
    __shared__ float sm[4];
    int lane = threadIdx.x & 63, w = threadIdx.x >> 6;
    if (lane == 0) sm[w] = acc;
    __syncthreads();
    if (threadIdx.x == 0)
        atomicAdd(out, -(sm[0] + sm[1] + sm[2] + sm[3]) / (float)N);
}

extern "C" void kernel_launch(void* const* d_in, const int* in_sizes, int n_in,
                              void* d_out, int out_size, void* d_ws, size_t ws_size,
                              hipStream_t stream) {
    const float*  scores = (const float*)d_in[0];
    const float4* pred   = (const float4*)d_in[1];
    const float4* gt     = (const float4*)d_in[2];
    float* out = (float*)d_out;

    int N = in_sizes[0];          // 20000 pred rows
    int M = in_sizes[2] / 4;      // 4000 gt boxes

    // workspace layout (16B-aligned offsets)
    char* ws = (char*)d_ws;
    float4*   sgt       = (float4*)(ws);                      // M*16      = 64000
    float4*   spred     = (float4*)(ws + 64000);              // N*16      = 320000
    float*    sga       = (float*) (ws + 384000);             // M*4       = 16000
    float*    spa       = (float*) (ws + 400000);             // N*4       = 80000
    int*      sidx      = (int*)   (ws + 480000);             // N*4       = 80000
    unsigned* flags     = (unsigned*)(ws + 560000);           // N*4       = 80000
    unsigned* bin_start = (unsigned*)(ws + 640000);           // (NB+1)*4

    k_prep<<<dim3(1), dim3(1024), 0, stream>>>(
        pred, gt, N, M, sgt, sga, spred, spa, sidx, flags, bin_start, out);

    int rb = (N + 511) / 512;                                 // 40
    k_pair<<<dim3(rb, CCH), dim3(256), 0, stream>>>(
        spred, spa, sgt, sga, bin_start, flags, N);

    k_loss<<<dim3(80), dim3(256), 0, stream>>>(scores, flags, sidx, out, N);
}

// Round 6
// 107.438 us; speedup vs baseline: 1.0808x; 1.0345x over previous
//
#include <hip/hip_runtime.h>
#include <cstdint>

#define EPS_IOU 1e-6f
#define NB 64              // x1 bins for counting sort
#define XMAX 901.0f
#define CCH 32             // window chunks (grid.y), power of 2
#define LOG2_CCH 5

__device__ __forceinline__ int binof(float x) {
    int b = (int)(x * ((float)NB / XMAX));
    return b < 0 ? 0 : (b > NB - 1 ? NB - 1 : b);
}

// Stage 1: per-block LDS histograms of pred/gt x1 bins -> global atomicAdd.
__global__ __launch_bounds__(256) void k_hist(
    const float4* __restrict__ pred, const float4* __restrict__ gt,
    int N, int M, unsigned* __restrict__ hist_pred, unsigned* __restrict__ hist_gt)
{
    __shared__ unsigned h[2 * NB];
    int t = threadIdx.x;
    if (t < 2 * NB) h[t] = 0;
    __syncthreads();
    int idx = blockIdx.x * 256 + t;
    if (idx < N) {
        atomicAdd(&h[binof(pred[idx].x)], 1u);
    } else if (idx < N + M) {
        atomicAdd(&h[NB + binof(gt[idx - N].x)], 1u);
    }
    __syncthreads();
    if (t < 2 * NB && h[t])
        atomicAdd(t < NB ? &hist_pred[t] : &hist_gt[t - NB], h[t]);
}

// Stage 2: 64-lane shfl exclusive scan; wave0 -> gt, wave1 -> pred. Zero out.
__global__ __launch_bounds__(128) void k_scan(
    const unsigned* __restrict__ hist_pred, const unsigned* __restrict__ hist_gt,
    unsigned* __restrict__ cur_pred, unsigned* __restrict__ cur_gt,
    unsigned* __restrict__ bin_start, float* __restrict__ out)
{
    int lane = threadIdx.x & 63, w = threadIdx.x >> 6;
    unsigned v = (w == 0) ? hist_gt[lane] : hist_pred[lane];
    unsigned x = v;
    #pragma unroll
    for (int o = 1; o < 64; o <<= 1) {
        unsigned y = __shfl_up(x, o, 64);
        if (lane >= o) x += y;
    }
    unsigned excl = x - v;
    if (w == 0) {
        cur_gt[lane] = excl;
        bin_start[lane] = excl;
        if (lane == 63) bin_start[NB] = x;
    } else {
        cur_pred[lane] = excl;
    }
    if (threadIdx.x == 0) out[0] = 0.0f;
}

// Stage 3: scatter into bin-sorted arrays; precompute areas; zero flags.
__global__ __launch_bounds__(256) void k_scatter(
    const float4* __restrict__ pred, const float4* __restrict__ gt,
    int N, int M, unsigned* __restrict__ cur_pred, unsigned* __restrict__ cur_gt,
    float4* __restrict__ spred, float* __restrict__ spa, int* __restrict__ sidx,
    float4* __restrict__ sgt, float* __restrict__ sga,
    unsigned* __restrict__ flags)
{
    int idx = blockIdx.x * 256 + threadIdx.x;
    if (idx < N) {
        float4 p = pred[idx];
        unsigned pos = atomicAdd(&cur_pred[binof(p.x)], 1u);
        spred[pos] = p;
        spa[pos] = (p.z - p.x) * (p.w - p.y);
        sidx[pos] = idx;
        flags[idx] = 0u;
    } else if (idx < N + M) {
        float4 g = gt[idx - N];
        unsigned pos = atomicAdd(&cur_gt[binof(g.x)], 1u);
        sgt[pos] = g;
        sga[pos] = (g.z - g.x) * (g.w - g.y) + EPS_IOU;   // ga + eps
    }
}

// Stage 4: 2 sorted pred ranks per thread; wave-shared x-window -> scan only
// gt bins in window (wave-uniform j -> scalar loads). grid.y slices window.
// hit: iou >= 0.5  <=>  3*inter >= a1+ga+eps  <=>  fma(inter,3,-a1) >= ga'
__global__ __launch_bounds__(256) void k_pair(
    const float4* __restrict__ spred, const float* __restrict__ spa,
    const float4* __restrict__ sgt, const float* __restrict__ sga,
    const unsigned* __restrict__ bin_start, unsigned* __restrict__ flags,
    int N)
{
    const float scale = (float)NB / XMAX;
    int tid = threadIdx.x;
    int r0 = blockIdx.x * 512 + tid;
    int r1 = r0 + 256;
    int rr0 = r0 < N ? r0 : N - 1;
    int rr1 = r1 < N ? r1 : N - 1;
    float4 b0 = spred[rr0], b1 = spred[rr1];
    float a0 = spa[rr0], a1 = spa[rr1];

    // conservative window: gt overlaps only if gx1 in [bx1-101, bx2] (+slack)
    float lo = fminf(b0.x, b1.x) - 102.0f;
    float hi = fmaxf(b0.z, b1.z) + 1.0f;
    #pragma unroll
    for (int m = 32; m >= 1; m >>= 1) {
        lo = fminf(lo, __shfl_xor(lo, m, 64));
        hi = fmaxf(hi, __shfl_xor(hi, m, 64));
    }
    int ilo = (int)(lo * scale); ilo = ilo < 0 ? 0 : (ilo > NB - 1 ? NB - 1 : ilo);
    int ihi = (int)(hi * scale); ihi = ihi < 0 ? 0 : (ihi > NB - 1 ? NB - 1 : ihi);
    ilo = __builtin_amdgcn_readfirstlane(ilo);
    ihi = __builtin_amdgcn_readfirstlane(ihi);
    int js0 = (int)bin_start[ilo];
    int je0 = (int)bin_start[ihi + 1];
    int len = je0 - js0;
    int c = (int)blockIdx.y;
    int js = js0 + ((len * c) >> LOG2_CCH);
    int je = js0 + ((len * (c + 1)) >> LOG2_CCH);

    bool f0 = false, f1 = false;
    #pragma unroll 4
    for (int j = js; j < je; ++j) {
        float4 g = sgt[j];                 // uniform -> s_load_dwordx4
        float ga = sga[j];                 // uniform -> s_load_dword
        {
            float dx = fmaxf(fminf(b0.z, g.z) - fmaxf(b0.x, g.x), 0.0f);
            float dy = fmaxf(fminf(b0.w, g.w) - fmaxf(b0.y, g.y), 0.0f);
            f0 |= (fmaf(dx * dy, 3.0f, -a0) >= ga);
        }
        {
            float dx = fmaxf(fminf(b1.z, g.z) - fmaxf(b1.x, g.x), 0.0f);
            float dy = fmaxf(fminf(b1.w, g.w) - fmaxf(b1.y, g.y), 0.0f);
            f1 |= (fmaf(dx * dy, 3.0f, -a1) >= ga);
        }
    }
    if (f0 && r0 < N) atomicOr(&flags[r0], 1u);
    if (f1 && r1 < N) atomicOr(&flags[r1], 1u);
}

// Stage 5: per-rank BCE (score gathered via sidx), block reduce, atomicAdd.
__global__ __launch_bounds__(256) void k_loss(
    const float* __restrict__ scores, const unsigned* __restrict__ flags,
    const int* __restrict__ sidx, float* __restrict__ out, int N)
{
    float acc = 0.0f;
    for (int r = blockIdx.x * 256 + threadIdx.x; r < N; r += gridDim.x * 256) {
        float p = scores[sidx[r]];
        float lp = fmaxf(logf(p),    -100.0f);
        float l1 = fmaxf(log1pf(-p), -100.0f);
        acc += flags[r] ? lp : l1;
    }
    for (int o = 32; o > 0; o >>= 1) acc += __shfl_down(acc, o, 64);
    __shared__ float sm[4];
    int lane = threadIdx.x & 63, w = threadIdx.x >> 6;
    if (lane == 0) sm[w] = acc;
    __syncthreads();
    if (threadIdx.x == 0)
        atomicAdd(out, -(sm[0] + sm[1] + sm[2] + sm[3]) / (float)N);
}

extern "C" void kernel_launch(void* const* d_in, const int* in_sizes, int n_in,
                              void* d_out, int out_size, void* d_ws, size_t ws_size,
                              hipStream_t stream) {
    const float*  scores = (const float*)d_in[0];
    const float4* pred   = (const float4*)d_in[1];
    const float4* gt     = (const float4*)d_in[2];
    float* out = (float*)d_out;

    int N = in_sizes[0];          // 20000 pred rows
    int M = in_sizes[2] / 4;      // 4000 gt boxes

    // workspace layout (16B-aligned offsets)
    char* ws = (char*)d_ws;
    float4*   sgt       = (float4*)(ws);                      // M*16  = 64000
    float4*   spred     = (float4*)(ws + 64000);              // N*16  = 320000
    float*    sga       = (float*) (ws + 384000);             // M*4   = 16000
    float*    spa       = (float*) (ws + 400000);             // N*4   = 80000
    int*      sidx      = (int*)   (ws + 480000);             // N*4   = 80000
    unsigned* flags     = (unsigned*)(ws + 560000);           // N*4   = 80000
    unsigned* hist_pred = (unsigned*)(ws + 640000);           // 256 B
    unsigned* hist_gt   = (unsigned*)(ws + 640256);           // 256 B
    unsigned* cur_pred  = (unsigned*)(ws + 640512);           // 256 B
    unsigned* cur_gt    = (unsigned*)(ws + 640768);           // 256 B
    unsigned* bin_start = (unsigned*)(ws + 641024);           // 260 B

    hipMemsetAsync(ws + 640000, 0, 512, stream);              // hists only

    int eb = (N + M + 255) / 256;                             // 94
    k_hist<<<dim3(eb), dim3(256), 0, stream>>>(pred, gt, N, M, hist_pred, hist_gt);
    k_scan<<<dim3(1), dim3(128), 0, stream>>>(hist_pred, hist_gt, cur_pred, cur_gt, bin_start, out);
    k_scatter<<<dim3(eb), dim3(256), 0, stream>>>(pred, gt, N, M, cur_pred, cur_gt,
                                                  spred, spa, sidx, sgt, sga, flags);

    int rb = (N + 511) / 512;                                 // 40
    k_pair<<<dim3(rb, CCH), dim3(256), 0, stream>>>(spred, spa, sgt, sga, bin_start, flags, N);

    k_loss<<<dim3(80), dim3(256), 0, stream>>>(scores, flags, sidx, out, N);
}